// Round 1
// baseline (182.985 us; speedup 1.0000x reference)
//
#include <hip/hip_runtime.h>

// BiAlignLayer collapses algebraically:
//   softmax rows/cols sum to 1  =>  mean over seq of weighted_i / weighted_j
//   equal mean(i) / mean(j) exactly.  With u = mean_l(i) - mean_m(j):
//   out = 0.5 * ( relu(u@W + b) + relu(-u@W + b) )
// Stage 1: streaming reduce (i - j) over L  (HBM-bound, ~128 MB read)
// Stage 2: [B,D] x [D,NN] matvec + bias + dual relu (L2-resident W)

#define BB 32
#define LL 1024
#define DD 512
#define NNN 512
#define SPLIT 16
#define ROWS (LL / SPLIT)          // 64 rows per chunk
#define NVEC (ROWS * DD / 4)       // 8192 float4 per chunk

__global__ __launch_bounds__(256) void bialign_stage1(
    const float* __restrict__ gi, const float* __restrict__ gj,
    float* __restrict__ part) {
    const int blk = blockIdx.x;            // b*SPLIT + s
    const int b = blk >> 4;                // / SPLIT
    const int s = blk & (SPLIT - 1);
    const size_t base = (size_t)b * LL * DD + (size_t)s * ROWS * DD;
    const float4* i4 = (const float4*)(gi + base);
    const float4* j4 = (const float4*)(gj + base);
    const int t = threadIdx.x;

    // stride 256 float4 = 1024 floats = 2 rows -> each thread's d-phase is
    // constant: phase(t) = (4t) mod 512. Threads t and t+128 share a phase.
    float4 acc = make_float4(0.f, 0.f, 0.f, 0.f);
    #pragma unroll 4
    for (int k = t; k < NVEC; k += 256) {
        float4 a = i4[k];
        float4 c = j4[k];
        acc.x += a.x - c.x;
        acc.y += a.y - c.y;
        acc.z += a.z - c.z;
        acc.w += a.w - c.w;
    }

    __shared__ float sm[DD];
    if (t < 128) {
        ((float4*)sm)[t] = acc;            // phase = 4t
    }
    __syncthreads();
    if (t >= 128) {
        const int p = t - 128;             // same phase slot
        float4 cur = ((float4*)sm)[p];
        cur.x += acc.x; cur.y += acc.y; cur.z += acc.z; cur.w += acc.w;
        ((float4*)sm)[p] = cur;
    }
    __syncthreads();
    if (t < 128) {
        ((float4*)(part + (size_t)blk * DD))[t] = ((float4*)sm)[t];
    }
}

#define NSPLIT 4                            // 512 outputs / 128 threads

__global__ __launch_bounds__(128) void bialign_stage2(
    const float* __restrict__ part, const float* __restrict__ W,
    const float* __restrict__ bias, float* __restrict__ out) {
    const int b = blockIdx.x;
    const int ns = blockIdx.y;
    const int t = threadIdx.x;              // 128

    __shared__ float u[DD];
    // u[d] = (1/L) * sum over SPLIT partials
    for (int d = t; d < DD; d += 128) {
        const float* p = part + (size_t)b * SPLIT * DD + d;
        float sum = 0.f;
        #pragma unroll
        for (int k = 0; k < SPLIT; ++k) sum += p[(size_t)k * DD];
        u[d] = sum * (1.0f / (float)LL);
    }
    __syncthreads();

    const int n = ns * 128 + t;
    float acc = 0.f;
    #pragma unroll 8
    for (int d = 0; d < DD; ++d) {
        acc = fmaf(u[d], W[(size_t)d * NNN + n], acc);
    }
    const float bb = bias[n];
    const float r = 0.5f * (fmaxf(acc + bb, 0.f) + fmaxf(bb - acc, 0.f));
    out[(size_t)b * NNN + n] = r;
}

extern "C" void kernel_launch(void* const* d_in, const int* in_sizes, int n_in,
                              void* d_out, int out_size, void* d_ws, size_t ws_size,
                              hipStream_t stream) {
    const float* gi   = (const float*)d_in[0];   // [B, L, D]
    const float* gj   = (const float*)d_in[1];   // [B, L, D]
    const float* W    = (const float*)d_in[2];   // [D, NN]
    const float* bias = (const float*)d_in[3];   // [NN]
    float* out = (float*)d_out;                  // [B, NN]
    float* part = (float*)d_ws;                  // B*SPLIT*D floats = 1 MB

    bialign_stage1<<<BB * SPLIT, 256, 0, stream>>>(gi, gj, part);
    bialign_stage2<<<dim3(BB, NSPLIT), 128, 0, stream>>>(part, W, bias, out);
}

// Round 2
// 169.303 us; speedup vs baseline: 1.0808x; 1.0808x over previous
//
#include <hip/hip_runtime.h>

// BiAlignLayer collapses algebraically:
//   softmax rows/cols sum to 1  =>  mean over seq of weighted_i / weighted_j
//   equal mean(i) / mean(j) exactly.  With u = mean_l(i) - mean_m(j):
//   out = 0.5 * ( relu(u@W + b) + relu(-u@W + b) )
// Stage 1: streaming reduce (i - j) over L  (HBM-bound, ~128 MB read)
//   R2: 1024-thread blocks -> 32 waves/CU (was 8); full unroll, 2 accumulators.
// Stage 2: [B,D] x [D,NN] matvec + bias + dual relu (L2-resident W)
//   R2: K split 2-way across threads to halve the dependent-load chain.

#define BB 32
#define LL 1024
#define DD 512
#define NNN 512
#define SPLIT 16
#define ROWS (LL / SPLIT)          // 64 rows per chunk
#define NVEC (ROWS * DD / 4)       // 8192 float4 per chunk
#define T1 1024                    // stage1 block size
#define PERT (NVEC / T1)           // 8 float4-pairs per thread

__global__ __launch_bounds__(T1, 8) void bialign_stage1(
    const float* __restrict__ gi, const float* __restrict__ gj,
    float* __restrict__ part) {
    const int blk = blockIdx.x;            // b*SPLIT + s
    const int b = blk >> 4;                // / SPLIT
    const int s = blk & (SPLIT - 1);
    const size_t base = (size_t)b * LL * DD + (size_t)s * ROWS * DD;
    const float4* i4 = (const float4*)(gi + base);
    const float4* j4 = (const float4*)(gj + base);
    const int t = threadIdx.x;

    // stride T1 float4 = 4096 floats = 8 rows -> each thread's d-phase is
    // constant: phase(t) = (4t) mod 512. Threads t mod 128 share a phase;
    // 8 phase-groups (t>>7).
    float4 acc0 = make_float4(0.f, 0.f, 0.f, 0.f);
    float4 acc1 = make_float4(0.f, 0.f, 0.f, 0.f);
    #pragma unroll
    for (int it = 0; it < PERT; it += 2) {
        float4 a0 = i4[t + it * T1];
        float4 c0 = j4[t + it * T1];
        float4 a1 = i4[t + (it + 1) * T1];
        float4 c1 = j4[t + (it + 1) * T1];
        acc0.x += a0.x - c0.x; acc0.y += a0.y - c0.y;
        acc0.z += a0.z - c0.z; acc0.w += a0.w - c0.w;
        acc1.x += a1.x - c1.x; acc1.y += a1.y - c1.y;
        acc1.z += a1.z - c1.z; acc1.w += a1.w - c1.w;
    }
    acc0.x += acc1.x; acc0.y += acc1.y; acc0.z += acc1.z; acc0.w += acc1.w;

    // 8 phase-groups of 128 threads each -> LDS [8][512] floats (16 KB)
    __shared__ float sm[8 * DD];
    float4* sm4 = (float4*)sm;
    sm4[(t >> 7) * 128 + (t & 127)] = acc0;     // group g, slot p = t&127
    __syncthreads();
    if (t < 128) {
        float4 s0 = sm4[t];
        #pragma unroll
        for (int g = 1; g < 8; ++g) {
            float4 v = sm4[g * 128 + t];
            s0.x += v.x; s0.y += v.y; s0.z += v.z; s0.w += v.w;
        }
        ((float4*)(part + (size_t)blk * DD))[t] = s0;
    }
}

// Stage 2: grid (B, 4) blocks of 256. Block (b, ns) computes out[b, ns*128 .. +127].
// Threads t<128 accumulate d=[0,256) for col ns*128+t; t>=128 accumulate d=[256,512)
// for col ns*128+(t-128); combine in LDS.
__global__ __launch_bounds__(256) void bialign_stage2(
    const float* __restrict__ part, const float* __restrict__ W,
    const float* __restrict__ bias, float* __restrict__ out) {
    const int b = blockIdx.x;
    const int ns = blockIdx.y;
    const int t = threadIdx.x;              // 256

    __shared__ float u[DD];
    __shared__ float psum[256];
    // u[d] = (1/L) * sum over SPLIT partials
    for (int d = t; d < DD; d += 256) {
        const float* p = part + (size_t)b * SPLIT * DD + d;
        float sum = 0.f;
        #pragma unroll
        for (int k = 0; k < SPLIT; ++k) sum += p[(size_t)k * DD];
        u[d] = sum * (1.0f / (float)LL);
    }
    __syncthreads();

    const int col = ns * 128 + (t & 127);
    const int d0 = (t >> 7) * 256;          // 0 or 256
    float acc = 0.f;
    #pragma unroll 8
    for (int d = 0; d < 256; ++d) {
        acc = fmaf(u[d0 + d], W[(size_t)(d0 + d) * NNN + col], acc);
    }
    psum[t] = acc;
    __syncthreads();
    if (t < 128) {
        const float dot = psum[t] + psum[t + 128];
        const float bb = bias[col];
        const float r = 0.5f * (fmaxf(dot + bb, 0.f) + fmaxf(bb - dot, 0.f));
        out[(size_t)b * NNN + col] = r;
    }
}

extern "C" void kernel_launch(void* const* d_in, const int* in_sizes, int n_in,
                              void* d_out, int out_size, void* d_ws, size_t ws_size,
                              hipStream_t stream) {
    const float* gi   = (const float*)d_in[0];   // [B, L, D]
    const float* gj   = (const float*)d_in[1];   // [B, L, D]
    const float* W    = (const float*)d_in[2];   // [D, NN]
    const float* bias = (const float*)d_in[3];   // [NN]
    float* out = (float*)d_out;                  // [B, NN]
    float* part = (float*)d_ws;                  // B*SPLIT*D floats = 1 MB

    bialign_stage1<<<BB * SPLIT, T1, 0, stream>>>(gi, gj, part);
    bialign_stage2<<<dim3(BB, 4), 256, 0, stream>>>(part, W, bias, out);
}

// Round 3
// 166.198 us; speedup vs baseline: 1.1010x; 1.0187x over previous
//
#include <hip/hip_runtime.h>

// BiAlignLayer collapses algebraically:
//   softmax rows/cols sum to 1  =>  mean over seq of weighted_i / weighted_j
//   equal mean(i) / mean(j) exactly.  With u = mean_l(i) - mean_m(j):
//   out = 0.5 * ( relu(u@W + b) + relu(-u@W + b) )
// Stage 1: streaming reduce (i - j) over L  (HBM-bound, ~128 MB read)
//   R3: anti-partition-camping window rotation. R2 showed BW stuck at
//   1.5 TB/s independent of occupancy AND of L3-vs-HBM residency ->
//   channel hotspotting from 128KB-congruent lockstep access. Each block
//   now visits its 8x16KB windows in a per-block-rotated order, i and j
//   streams decorrelated.
// Stage 2: [B,D] x [D,NN] matvec + bias + dual relu (unchanged control)

#define BB 32
#define LL 1024
#define DD 512
#define NNN 512
#define SPLIT 16
#define ROWS (LL / SPLIT)          // 64 rows per chunk
#define NVEC (ROWS * DD / 4)       // 8192 float4 per chunk per stream
#define T1 1024                    // stage1 block size
#define NWIN (NVEC / T1)           // 8 windows of 16 KB

__global__ __launch_bounds__(T1, 8) void bialign_stage1(
    const float* __restrict__ gi, const float* __restrict__ gj,
    float* __restrict__ part) {
    const int blk = blockIdx.x;            // b*SPLIT + s
    const int b = blk >> 4;                // / SPLIT
    const int s = blk & (SPLIT - 1);
    const size_t base = (size_t)b * LL * DD + (size_t)s * ROWS * DD;
    const float4* i4 = (const float4*)(gi + base);
    const float4* j4 = (const float4*)(gj + base);
    const int t = threadIdx.x;

    // Window-visit order rotated per block so concurrent blocks cover all
    // 8 window offsets (full 128 KB interleave period) at every instant.
    const int rot  = (blk * 5) & (NWIN - 1);
    const int rotj = (rot + 3) & (NWIN - 1);

    // Window stride = T1 float4 = 4096 floats == 0 mod 512 -> each thread's
    // d-phase is constant: phase(t) = (4t) mod 512; 8 phase-groups (t>>7).
    float4 acc0 = make_float4(0.f, 0.f, 0.f, 0.f);
    float4 acc1 = make_float4(0.f, 0.f, 0.f, 0.f);
    #pragma unroll
    for (int w = 0; w < NWIN; w += 2) {
        const int wi0 = ((w + 0 + rot)  & (NWIN - 1)) * T1 + t;
        const int wi1 = ((w + 1 + rot)  & (NWIN - 1)) * T1 + t;
        const int wj0 = ((w + 0 + rotj) & (NWIN - 1)) * T1 + t;
        const int wj1 = ((w + 1 + rotj) & (NWIN - 1)) * T1 + t;
        float4 a0 = i4[wi0];
        float4 c0 = j4[wj0];
        float4 a1 = i4[wi1];
        float4 c1 = j4[wj1];
        acc0.x += a0.x - c0.x; acc0.y += a0.y - c0.y;
        acc0.z += a0.z - c0.z; acc0.w += a0.w - c0.w;
        acc1.x += a1.x - c1.x; acc1.y += a1.y - c1.y;
        acc1.z += a1.z - c1.z; acc1.w += a1.w - c1.w;
    }
    acc0.x += acc1.x; acc0.y += acc1.y; acc0.z += acc1.z; acc0.w += acc1.w;

    // 8 phase-groups of 128 threads each -> LDS [8][512] floats (16 KB)
    __shared__ float sm[8 * DD];
    float4* sm4 = (float4*)sm;
    sm4[(t >> 7) * 128 + (t & 127)] = acc0;     // group g, slot p = t&127
    __syncthreads();
    if (t < 128) {
        float4 s0 = sm4[t];
        #pragma unroll
        for (int g = 1; g < 8; ++g) {
            float4 v = sm4[g * 128 + t];
            s0.x += v.x; s0.y += v.y; s0.z += v.z; s0.w += v.w;
        }
        ((float4*)(part + (size_t)blk * DD))[t] = s0;
    }
}

// Stage 2: grid (B, 4) blocks of 256. Block (b, ns) computes out[b, ns*128 .. +127].
// Threads t<128 accumulate d=[0,256) for col ns*128+t; t>=128 accumulate d=[256,512)
// for col ns*128+(t-128); combine in LDS.
__global__ __launch_bounds__(256) void bialign_stage2(
    const float* __restrict__ part, const float* __restrict__ W,
    const float* __restrict__ bias, float* __restrict__ out) {
    const int b = blockIdx.x;
    const int ns = blockIdx.y;
    const int t = threadIdx.x;              // 256

    __shared__ float u[DD];
    __shared__ float psum[256];
    // u[d] = (1/L) * sum over SPLIT partials
    for (int d = t; d < DD; d += 256) {
        const float* p = part + (size_t)b * SPLIT * DD + d;
        float sum = 0.f;
        #pragma unroll
        for (int k = 0; k < SPLIT; ++k) sum += p[(size_t)k * DD];
        u[d] = sum * (1.0f / (float)LL);
    }
    __syncthreads();

    const int col = ns * 128 + (t & 127);
    const int d0 = (t >> 7) * 256;          // 0 or 256
    float acc = 0.f;
    #pragma unroll 8
    for (int d = 0; d < 256; ++d) {
        acc = fmaf(u[d0 + d], W[(size_t)(d0 + d) * NNN + col], acc);
    }
    psum[t] = acc;
    __syncthreads();
    if (t < 128) {
        const float dot = psum[t] + psum[t + 128];
        const float bb = bias[col];
        const float r = 0.5f * (fmaxf(dot + bb, 0.f) + fmaxf(bb - dot, 0.f));
        out[(size_t)b * NNN + col] = r;
    }
}

extern "C" void kernel_launch(void* const* d_in, const int* in_sizes, int n_in,
                              void* d_out, int out_size, void* d_ws, size_t ws_size,
                              hipStream_t stream) {
    const float* gi   = (const float*)d_in[0];   // [B, L, D]
    const float* gj   = (const float*)d_in[1];   // [B, L, D]
    const float* W    = (const float*)d_in[2];   // [D, NN]
    const float* bias = (const float*)d_in[3];   // [NN]
    float* out = (float*)d_out;                  // [B, NN]
    float* part = (float*)d_ws;                  // B*SPLIT*D floats = 1 MB

    bialign_stage1<<<BB * SPLIT, T1, 0, stream>>>(gi, gj, part);
    bialign_stage2<<<dim3(BB, 4), 256, 0, stream>>>(part, W, bias, out);
}

// Round 4
// 155.597 us; speedup vs baseline: 1.1760x; 1.0681x over previous
//
#include <hip/hip_runtime.h>

// BiAlignLayer collapses algebraically:
//   softmax rows/cols sum to 1  =>  mean over seq of weighted_i / weighted_j
//   equal mean(i) / mean(j) exactly.  With u = mean_l(i) - mean_m(j):
//   out = 0.5 * ( relu(u@W + b) + relu(-u@W + b) )
// Stage 1: streaming reduce (i - j) over L  (~128 MB read).
//   R4: BW stuck at ~3 TB/s aggregate (12 GB/s/CU) independent of occupancy
//   (R2) and access order (R3) -> theory: per-CU L1 miss-queue cap
//   (~4.5 KB lines in flight / ~900 cyc). Experiment: nontemporal loads
//   (bypass L1 retention) + 8 loads in flight per thread.
// Stage 2: [B,D] x [D,NN] matvec + bias + dual relu (unchanged control)

#define BB 32
#define LL 1024
#define DD 512
#define NNN 512
#define SPLIT 16
#define ROWS (LL / SPLIT)          // 64 rows per chunk
#define NVEC (ROWS * DD / 4)       // 8192 float4 per chunk per stream
#define T1 1024                    // stage1 block size
#define NWIN (NVEC / T1)           // 8 windows

typedef float f4 __attribute__((ext_vector_type(4)));

__global__ __launch_bounds__(T1, 8) void bialign_stage1(
    const float* __restrict__ gi, const float* __restrict__ gj,
    float* __restrict__ part) {
    const int blk = blockIdx.x;            // b*SPLIT + s
    const int b = blk >> 4;                // / SPLIT
    const int s = blk & (SPLIT - 1);
    const size_t base = (size_t)b * LL * DD + (size_t)s * ROWS * DD;
    const f4* i4 = (const f4*)(gi + base);
    const f4* j4 = (const f4*)(gj + base);
    const int t = threadIdx.x;

    // Window stride = T1 f4 = 4096 floats == 0 mod 512 -> each thread's
    // d-phase is constant: phase(t) = (4t) mod 512; 8 phase-groups (t>>7).
    f4 acc0 = 0.f, acc1 = 0.f, acc2 = 0.f, acc3 = 0.f;
    #pragma unroll
    for (int w = 0; w < NWIN; w += 4) {
        // 8 independent nontemporal loads issued before any use
        f4 a0 = __builtin_nontemporal_load(i4 + (size_t)(w + 0) * T1 + t);
        f4 a1 = __builtin_nontemporal_load(i4 + (size_t)(w + 1) * T1 + t);
        f4 a2 = __builtin_nontemporal_load(i4 + (size_t)(w + 2) * T1 + t);
        f4 a3 = __builtin_nontemporal_load(i4 + (size_t)(w + 3) * T1 + t);
        f4 c0 = __builtin_nontemporal_load(j4 + (size_t)(w + 0) * T1 + t);
        f4 c1 = __builtin_nontemporal_load(j4 + (size_t)(w + 1) * T1 + t);
        f4 c2 = __builtin_nontemporal_load(j4 + (size_t)(w + 2) * T1 + t);
        f4 c3 = __builtin_nontemporal_load(j4 + (size_t)(w + 3) * T1 + t);
        acc0 += a0 - c0;
        acc1 += a1 - c1;
        acc2 += a2 - c2;
        acc3 += a3 - c3;
    }
    acc0 += acc1;
    acc2 += acc3;
    acc0 += acc2;

    // 8 phase-groups of 128 threads each -> LDS [8][512] floats (16 KB)
    __shared__ float sm[8 * DD];
    f4* sm4 = (f4*)sm;
    sm4[(t >> 7) * 128 + (t & 127)] = acc0;     // group g, slot p = t&127
    __syncthreads();
    if (t < 128) {
        f4 s0 = sm4[t];
        #pragma unroll
        for (int g = 1; g < 8; ++g) {
            s0 += sm4[g * 128 + t];
        }
        ((f4*)(part + (size_t)blk * DD))[t] = s0;
    }
}

// Stage 2: grid (B, 4) blocks of 256. Block (b, ns) computes out[b, ns*128 .. +127].
// Threads t<128 accumulate d=[0,256) for col ns*128+t; t>=128 accumulate d=[256,512)
// for col ns*128+(t-128); combine in LDS.
__global__ __launch_bounds__(256) void bialign_stage2(
    const float* __restrict__ part, const float* __restrict__ W,
    const float* __restrict__ bias, float* __restrict__ out) {
    const int b = blockIdx.x;
    const int ns = blockIdx.y;
    const int t = threadIdx.x;              // 256

    __shared__ float u[DD];
    __shared__ float psum[256];
    // u[d] = (1/L) * sum over SPLIT partials
    for (int d = t; d < DD; d += 256) {
        const float* p = part + (size_t)b * SPLIT * DD + d;
        float sum = 0.f;
        #pragma unroll
        for (int k = 0; k < SPLIT; ++k) sum += p[(size_t)k * DD];
        u[d] = sum * (1.0f / (float)LL);
    }
    __syncthreads();

    const int col = ns * 128 + (t & 127);
    const int d0 = (t >> 7) * 256;          // 0 or 256
    float acc = 0.f;
    #pragma unroll 8
    for (int d = 0; d < 256; ++d) {
        acc = fmaf(u[d0 + d], W[(size_t)(d0 + d) * NNN + col], acc);
    }
    psum[t] = acc;
    __syncthreads();
    if (t < 128) {
        const float dot = psum[t] + psum[t + 128];
        const float bb = bias[col];
        const float r = 0.5f * (fmaxf(dot + bb, 0.f) + fmaxf(bb - dot, 0.f));
        out[(size_t)b * NNN + col] = r;
    }
}

extern "C" void kernel_launch(void* const* d_in, const int* in_sizes, int n_in,
                              void* d_out, int out_size, void* d_ws, size_t ws_size,
                              hipStream_t stream) {
    const float* gi   = (const float*)d_in[0];   // [B, L, D]
    const float* gj   = (const float*)d_in[1];   // [B, L, D]
    const float* W    = (const float*)d_in[2];   // [D, NN]
    const float* bias = (const float*)d_in[3];   // [NN]
    float* out = (float*)d_out;                  // [B, NN]
    float* part = (float*)d_ws;                  // B*SPLIT*D floats = 1 MB

    bialign_stage1<<<BB * SPLIT, T1, 0, stream>>>(gi, gj, part);
    bialign_stage2<<<dim3(BB, 4), 256, 0, stream>>>(part, W, bias, out);
}

// Round 5
// 155.452 us; speedup vs baseline: 1.1771x; 1.0009x over previous
//
#include <hip/hip_runtime.h>

// BiAlignLayer collapses algebraically:
//   softmax rows/cols sum to 1  =>  mean over seq of weighted_i / weighted_j
//   equal mean(i) / mean(j) exactly.  With u = mean_l(i) - mean_m(j):
//   out = 0.5 * ( relu(u@W + b) + relu(-u@W + b) )
// Stage 1: streaming reduce (i - j) over L  (~128 MB read).
//   R4 result: nontemporal loads 3.0 -> 4.2 TB/s (per-CU L1 miss-queue
//   theory supported). R5: hold ALL 16 nt loads in flight per thread
//   (launch_bounds 1024,4 -> 128 VGPR cap; was 8 -> 64 VGPR forcing
//   batch-of-8 drain). Occupancy above 16 waves/CU proven worthless (R2),
//   so trading waves for per-wave memory depth is free.
// Stage 2: [B,D] x [D,NN] matvec + bias + dual relu (unchanged control)

#define BB 32
#define LL 1024
#define DD 512
#define NNN 512
#define SPLIT 16
#define ROWS (LL / SPLIT)          // 64 rows per chunk
#define NVEC (ROWS * DD / 4)       // 8192 float4 per chunk per stream
#define T1 1024                    // stage1 block size
#define NWIN (NVEC / T1)           // 8 windows per stream

typedef float f4 __attribute__((ext_vector_type(4)));

__global__ __launch_bounds__(T1, 4) void bialign_stage1(
    const float* __restrict__ gi, const float* __restrict__ gj,
    float* __restrict__ part) {
    const int blk = blockIdx.x;            // b*SPLIT + s
    const int b = blk >> 4;                // / SPLIT
    const int s = blk & (SPLIT - 1);
    const size_t base = (size_t)b * LL * DD + (size_t)s * ROWS * DD;
    const f4* i4 = (const f4*)(gi + base);
    const f4* j4 = (const f4*)(gj + base);
    const int t = threadIdx.x;

    // All 16 independent nt loads issued before any use: 256 B payload
    // = 64 VGPRs, allowed by the 128-VGPR cap.
    f4 a[NWIN], c[NWIN];
    #pragma unroll
    for (int w = 0; w < NWIN; ++w) {
        a[w] = __builtin_nontemporal_load(i4 + (size_t)w * T1 + t);
        c[w] = __builtin_nontemporal_load(j4 + (size_t)w * T1 + t);
    }

    // Window stride = T1 f4 = 4096 floats == 0 mod 512 -> each thread's
    // d-phase is constant: phase(t) = (4t) mod 512; 8 phase-groups (t>>7).
    f4 acc0 = 0.f, acc1 = 0.f, acc2 = 0.f, acc3 = 0.f;
    #pragma unroll
    for (int w = 0; w < NWIN; w += 4) {
        acc0 += a[w + 0] - c[w + 0];
        acc1 += a[w + 1] - c[w + 1];
        acc2 += a[w + 2] - c[w + 2];
        acc3 += a[w + 3] - c[w + 3];
    }
    acc0 += acc1;
    acc2 += acc3;
    acc0 += acc2;

    // 8 phase-groups of 128 threads each -> LDS [8][512] floats (16 KB)
    __shared__ float sm[8 * DD];
    f4* sm4 = (f4*)sm;
    sm4[(t >> 7) * 128 + (t & 127)] = acc0;     // group g, slot p = t&127
    __syncthreads();
    if (t < 128) {
        f4 s0 = sm4[t];
        #pragma unroll
        for (int g = 1; g < 8; ++g) {
            s0 += sm4[g * 128 + t];
        }
        ((f4*)(part + (size_t)blk * DD))[t] = s0;
    }
}

// Stage 2: grid (B, 4) blocks of 256. Block (b, ns) computes out[b, ns*128 .. +127].
// Threads t<128 accumulate d=[0,256) for col ns*128+t; t>=128 accumulate d=[256,512)
// for col ns*128+(t-128); combine in LDS.
__global__ __launch_bounds__(256) void bialign_stage2(
    const float* __restrict__ part, const float* __restrict__ W,
    const float* __restrict__ bias, float* __restrict__ out) {
    const int b = blockIdx.x;
    const int ns = blockIdx.y;
    const int t = threadIdx.x;              // 256

    __shared__ float u[DD];
    __shared__ float psum[256];
    // u[d] = (1/L) * sum over SPLIT partials
    for (int d = t; d < DD; d += 256) {
        const float* p = part + (size_t)b * SPLIT * DD + d;
        float sum = 0.f;
        #pragma unroll
        for (int k = 0; k < SPLIT; ++k) sum += p[(size_t)k * DD];
        u[d] = sum * (1.0f / (float)LL);
    }
    __syncthreads();

    const int col = ns * 128 + (t & 127);
    const int d0 = (t >> 7) * 256;          // 0 or 256
    float acc = 0.f;
    #pragma unroll 8
    for (int d = 0; d < 256; ++d) {
        acc = fmaf(u[d0 + d], W[(size_t)(d0 + d) * NNN + col], acc);
    }
    psum[t] = acc;
    __syncthreads();
    if (t < 128) {
        const float dot = psum[t] + psum[t + 128];
        const float bb = bias[col];
        const float r = 0.5f * (fmaxf(dot + bb, 0.f) + fmaxf(bb - dot, 0.f));
        out[(size_t)b * NNN + col] = r;
    }
}

extern "C" void kernel_launch(void* const* d_in, const int* in_sizes, int n_in,
                              void* d_out, int out_size, void* d_ws, size_t ws_size,
                              hipStream_t stream) {
    const float* gi   = (const float*)d_in[0];   // [B, L, D]
    const float* gj   = (const float*)d_in[1];   // [B, L, D]
    const float* W    = (const float*)d_in[2];   // [D, NN]
    const float* bias = (const float*)d_in[3];   // [NN]
    float* out = (float*)d_out;                  // [B, NN]
    float* part = (float*)d_ws;                  // B*SPLIT*D floats = 1 MB

    bialign_stage1<<<BB * SPLIT, T1, 0, stream>>>(gi, gj, part);
    bialign_stage2<<<dim3(BB, 4), 256, 0, stream>>>(part, W, bias, out);
}